// Round 1
// baseline (1137.787 us; speedup 1.0000x reference)
//
#include <hip/hip_runtime.h>

#define HID 2048
#define NH 16
#define DH 128
#define DFF 8192
#define BB 2
#define TT 2048
#define MROWS 4096   // B*T

typedef __bf16 bf16x8 __attribute__((ext_vector_type(8)));
typedef __bf16 bf16x4 __attribute__((ext_vector_type(4)));
typedef float  f32x4  __attribute__((ext_vector_type(4)));

__device__ __forceinline__ f32x4 mfma16(bf16x8 a, bf16x8 b, f32x4 c) {
    return __builtin_amdgcn_mfma_f32_16x16x32_bf16(a, b, c, 0, 0, 0);
}

__device__ __forceinline__ void gload_lds16(const __bf16* gsrc, __bf16* ldst) {
    __builtin_amdgcn_global_load_lds(
        (const __attribute__((address_space(1))) void*)gsrc,
        (__attribute__((address_space(3))) void*)ldst, 16, 0, 0);
}

// ---------------- weight transpose+convert: W[K][N] f32 -> Wt[N][K] bf16 ----
template<int K, int N>
__global__ __launch_bounds__(256) void transpose_bf16_kernel(
    const float* __restrict__ W, __bf16* __restrict__ Wt) {
    __shared__ float tile[64][65];
    int tx = threadIdx.x;          // 0..63
    int ty = threadIdx.y;          // 0..3
    int n0 = blockIdx.x * 64;
    int k0 = blockIdx.y * 64;
    #pragma unroll
    for (int i = 0; i < 16; i++) {
        int kk = ty * 16 + i;
        tile[tx][kk] = W[(size_t)(k0 + kk) * N + n0 + tx];
    }
    __syncthreads();
    #pragma unroll
    for (int i = 0; i < 16; i++) {
        int nn = ty * 16 + i;
        Wt[(size_t)(n0 + nn) * K + k0 + tx] = (__bf16)tile[nn][tx];
    }
}

// ---------------- LayerNorm f32 -> bf16 ------------------------------------
__global__ __launch_bounds__(256) void ln_kernel(
    const float* __restrict__ x, const float* __restrict__ gw,
    const float* __restrict__ gb, __bf16* __restrict__ out) {
    int row = blockIdx.x;
    int t = threadIdx.x;
    const float* xr = x + (size_t)row * HID;
    float4 v0 = *(const float4*)(xr + t * 8);
    float4 v1 = *(const float4*)(xr + t * 8 + 4);
    float xv[8] = {v0.x, v0.y, v0.z, v0.w, v1.x, v1.y, v1.z, v1.w};
    float s = 0.f, q = 0.f;
    #pragma unroll
    for (int j = 0; j < 8; j++) { s += xv[j]; q += xv[j] * xv[j]; }
    #pragma unroll
    for (int off = 1; off < 64; off <<= 1) {
        s += __shfl_xor(s, off);
        q += __shfl_xor(q, off);
    }
    __shared__ float ssum[4], ssq[4];
    if ((t & 63) == 0) { ssum[t >> 6] = s; ssq[t >> 6] = q; }
    __syncthreads();
    s = ssum[0] + ssum[1] + ssum[2] + ssum[3];
    q = ssq[0] + ssq[1] + ssq[2] + ssq[3];
    float mu = s * (1.0f / HID);
    float var = q * (1.0f / HID) - mu * mu;
    float rs = rsqrtf(var + 1e-5f);
    bf16x8 o;
    #pragma unroll
    for (int j = 0; j < 8; j++)
        o[j] = (__bf16)((xv[j] - mu) * rs * gw[t * 8 + j] + gb[t * 8 + j]);
    *(bf16x8*)(out + (size_t)row * HID + t * 8) = o;
}

// ---------------- GEMM: C[M,N] = A[M,K] * Bt[N,K]^T, m97 structure ---------
// EPI: 0=plain bf16, 1=V-transposed bf16 [B,NH,DH,T], 2=f32 +resid,
//      3=bf16 silu(+bias), 4=f32 +bias+resid
template<int EPI, int N, int K>
__global__ __launch_bounds__(256) void gemm_kernel(
    const __bf16* __restrict__ A, const __bf16* __restrict__ Bt,
    void* __restrict__ Cout, const float* __restrict__ resid,
    const float* __restrict__ bias) {
    __shared__ __align__(16) __bf16 As[128 * 32];
    __shared__ __align__(16) __bf16 Bs[128 * 32];
    int tid = threadIdx.x;
    int w = tid >> 6, l = tid & 63;
    int wr = w >> 1, wc = w & 1;
    int qi = l & 15, g = l >> 4;
    int row0 = blockIdx.y * 128, col0 = blockIdx.x * 128;

    f32x4 acc[4][4] = {};

    // staging source base: chunk c = w*2+i covers 16 rows of the tile
    const __bf16* Abase = A + (size_t)(row0 + w * 32 + (l >> 2)) * K + (l & 3) * 8;
    const __bf16* Bbase = Bt + (size_t)(col0 + w * 32 + (l >> 2)) * K + (l & 3) * 8;

    for (int k0 = 0; k0 < K; k0 += 32) {
        __syncthreads();
        #pragma unroll
        for (int i = 0; i < 2; i++) {
            gload_lds16(Abase + (size_t)i * 16 * K + k0, As + (w * 2 + i) * 512);
            gload_lds16(Bbase + (size_t)i * 16 * K + k0, Bs + (w * 2 + i) * 512);
        }
        __syncthreads();
        bf16x8 af[4], bfr[4];
        #pragma unroll
        for (int m = 0; m < 4; m++)
            af[m] = *(const bf16x8*)(As + (wr * 64 + m * 16 + qi) * 32 + g * 8);
        #pragma unroll
        for (int n = 0; n < 4; n++)
            bfr[n] = *(const bf16x8*)(Bs + (wc * 64 + n * 16 + qi) * 32 + g * 8);
        #pragma unroll
        for (int m = 0; m < 4; m++)
            #pragma unroll
            for (int n = 0; n < 4; n++)
                acc[m][n] = mfma16(af[m], bfr[n], acc[m][n]);
    }

    // epilogue: C/D layout col=lane&15, row=(lane>>4)*4+r
    #pragma unroll
    for (int m = 0; m < 4; m++) {
        #pragma unroll
        for (int n = 0; n < 4; n++) {
            int Rb = row0 + wr * 64 + m * 16 + g * 4;
            int C = col0 + wc * 64 + n * 16 + qi;
            if constexpr (EPI == 1) {
                bf16x4 pk;
                #pragma unroll
                for (int r = 0; r < 4; r++) pk[r] = (__bf16)acc[m][n][r];
                int b = Rb >> 11, t0 = Rb & 2047, hh = C >> 7, d = C & 127;
                *(bf16x4*)((__bf16*)Cout + ((size_t)(b * NH + hh) * DH + d) * TT + t0) = pk;
            } else {
                #pragma unroll
                for (int r = 0; r < 4; r++) {
                    int R = Rb + r;
                    float v = acc[m][n][r];
                    size_t idx = (size_t)R * N + C;
                    if constexpr (EPI == 0) {
                        ((__bf16*)Cout)[idx] = (__bf16)v;
                    } else if constexpr (EPI == 2) {
                        ((float*)Cout)[idx] = resid[idx] + v;
                    } else if constexpr (EPI == 3) {
                        float u = v + bias[C];
                        ((__bf16*)Cout)[idx] = (__bf16)(u / (1.f + __expf(-u)));
                    } else {
                        float u = v + bias[C];
                        ((float*)Cout)[idx] = resid[idx] + u;
                    }
                }
            }
        }
    }
}

// ---------------- flash attention ------------------------------------------
// q,k: bf16 [B*T, HID] (row-major as projected); vt: bf16 [B,NH,DH,T]
// out: bf16 [B*T, HID]
__global__ __launch_bounds__(256) void attn_kernel(
    const __bf16* __restrict__ qh, const __bf16* __restrict__ kh,
    const __bf16* __restrict__ vt, __bf16* __restrict__ out) {
    __shared__ __align__(16) __bf16 plds[4][16 * 32];
    int tid = threadIdx.x;
    int w = tid >> 6, l = tid & 63;
    int qi = l & 15, g = l >> 4;
    int bh = blockIdx.y;
    int b = bh >> 4, hd = bh & 15;
    int qbase = blockIdx.x * 64 + w * 16;
    int qg = qbase + qi;

    const __bf16* qrow = qh + ((size_t)b * TT + qg) * HID + hd * DH;
    const __bf16* kbase = kh + (size_t)b * TT * HID + hd * DH;
    const __bf16* vtb = vt + (size_t)bh * DH * TT;

    bf16x8 bq[4];
    #pragma unroll
    for (int kc = 0; kc < 4; kc++)
        bq[kc] = *(const bf16x8*)(qrow + kc * 32 + g * 8);

    f32x4 O[8] = {};
    float m_run = -3.0e38f, l_run = 0.f;
    const float scale = 0.08838834764831845f;   // 1/sqrt(128)
    int kv_end = qbase + 16;

    for (int kv0 = 0; kv0 < kv_end; kv0 += 32) {
        f32x4 st0 = {0.f, 0.f, 0.f, 0.f}, st1 = {0.f, 0.f, 0.f, 0.f};
        #pragma unroll
        for (int kc = 0; kc < 4; kc++) {
            bf16x8 ak0 = *(const bf16x8*)(kbase + (size_t)(kv0 + qi) * HID + kc * 32 + g * 8);
            bf16x8 ak1 = *(const bf16x8*)(kbase + (size_t)(kv0 + 16 + qi) * HID + kc * 32 + g * 8);
            st0 = mfma16(ak0, bq[kc], st0);   // S^T: col=q (l&15), row=kv (g*4+r)
            st1 = mfma16(ak1, bq[kc], st1);
        }
        float s[8];
        #pragma unroll
        for (int r = 0; r < 4; r++) { s[r] = st0[r] * scale; s[4 + r] = st1[r] * scale; }
        #pragma unroll
        for (int i = 0; i < 8; i++) {
            int kvg = kv0 + (i >> 2) * 16 + g * 4 + (i & 3);
            if (kvg > qg) s[i] = -3.0e38f;
        }
        float mt = s[0];
        #pragma unroll
        for (int i = 1; i < 8; i++) mt = fmaxf(mt, s[i]);
        mt = fmaxf(mt, __shfl_xor(mt, 16));
        mt = fmaxf(mt, __shfl_xor(mt, 32));
        float m_new = fmaxf(m_run, mt);
        float alpha = __expf(m_run - m_new);
        float p[8], ps = 0.f;
        #pragma unroll
        for (int i = 0; i < 8; i++) { p[i] = __expf(s[i] - m_new); ps += p[i]; }
        ps += __shfl_xor(ps, 16);
        ps += __shfl_xor(ps, 32);
        l_run = l_run * alpha + ps;
        m_run = m_new;

        bf16x4 p0, p1;
        #pragma unroll
        for (int r = 0; r < 4; r++) { p0[r] = (__bf16)p[r]; p1[r] = (__bf16)p[4 + r]; }
        *(bf16x4*)(&plds[w][qi * 32 + g * 4]) = p0;
        *(bf16x4*)(&plds[w][qi * 32 + 16 + g * 4]) = p1;

        float av[4];
        #pragma unroll
        for (int r = 0; r < 4; r++) av[r] = __shfl(alpha, (g << 4) | (g * 4 + r));
        #pragma unroll
        for (int oc = 0; oc < 8; oc++)
            #pragma unroll
            for (int r = 0; r < 4; r++) O[oc][r] *= av[r];

        bf16x8 ap = *(const bf16x8*)(&plds[w][qi * 32 + g * 8]);
        #pragma unroll
        for (int oc = 0; oc < 8; oc++) {
            bf16x8 bv = *(const bf16x8*)(vtb + (size_t)(oc * 16 + qi) * TT + kv0 + g * 8);
            O[oc] = mfma16(ap, bv, O[oc]);
        }
    }

    float linv[4];
    #pragma unroll
    for (int r = 0; r < 4; r++) {
        float lq = __shfl(l_run, (g << 4) | (g * 4 + r));
        linv[r] = 1.0f / lq;
    }
    __bf16* op = out + ((size_t)b * TT + qbase) * HID + hd * DH;
    #pragma unroll
    for (int oc = 0; oc < 8; oc++)
        #pragma unroll
        for (int r = 0; r < 4; r++)
            op[(size_t)(g * 4 + r) * HID + oc * 16 + qi] = (__bf16)(O[oc][r] * linv[r]);
}

// ---------------- launch ----------------------------------------------------
extern "C" void kernel_launch(void* const* d_in, const int* in_sizes, int n_in,
                              void* d_out, int out_size, void* d_ws, size_t ws_size,
                              hipStream_t stream) {
    const float* x    = (const float*)d_in[0];
    const float* Wq   = (const float*)d_in[2];
    const float* Wk   = (const float*)d_in[3];
    const float* Wv   = (const float*)d_in[4];
    const float* Wo   = (const float*)d_in[5];
    const float* ln1w = (const float*)d_in[6];
    const float* ln1b = (const float*)d_in[7];
    const float* ln2w = (const float*)d_in[8];
    const float* ln2b = (const float*)d_in[9];
    const float* W1   = (const float*)d_in[10];
    const float* b1   = (const float*)d_in[11];
    const float* W2   = (const float*)d_in[12];
    const float* b2   = (const float*)d_in[13];
    float* outp = (float*)d_out;

    char* ws = (char*)d_ws;
    const size_t SZ_W   = (size_t)HID * HID * 2;     //  8.4 MB
    const size_t SZ_WF  = (size_t)HID * DFF * 2;     // 33.5 MB
    const size_t SZ_ACT = (size_t)MROWS * HID * 2;   // 16.8 MB
    const size_t SZ_X32 = (size_t)MROWS * HID * 4;   // 33.5 MB

    __bf16* wqT  = (__bf16*)(ws);
    __bf16* wkT  = (__bf16*)(ws + SZ_W);
    __bf16* wvT  = (__bf16*)(ws + 2 * SZ_W);
    __bf16* woT  = (__bf16*)(ws + 3 * SZ_W);
    __bf16* w1T  = (__bf16*)(ws + 4 * SZ_W);
    __bf16* w2T  = (__bf16*)(ws + 4 * SZ_W + SZ_WF);
    __bf16* h    = (__bf16*)(ws + 4 * SZ_W + 2 * SZ_WF);            // h2 aliases h
    float*  x1   = (float*) (ws + 4 * SZ_W + 2 * SZ_WF + SZ_ACT);
    char*   base = ws + 4 * SZ_W + 2 * SZ_WF + SZ_ACT + SZ_X32;
    __bf16* qb   = (__bf16*)(base);
    __bf16* kb   = (__bf16*)(base + SZ_ACT);
    __bf16* vtb  = (__bf16*)(base + 2 * SZ_ACT);
    __bf16* attn = (__bf16*)(base + 3 * SZ_ACT);
    __bf16* mlp1 = (__bf16*)(base);                                  // aliases q/k/vt/attn

    dim3 blk256(256);
    // weight conversion
    transpose_bf16_kernel<HID, HID><<<dim3(32, 32), dim3(64, 4), 0, stream>>>(Wq, wqT);
    transpose_bf16_kernel<HID, HID><<<dim3(32, 32), dim3(64, 4), 0, stream>>>(Wk, wkT);
    transpose_bf16_kernel<HID, HID><<<dim3(32, 32), dim3(64, 4), 0, stream>>>(Wv, wvT);
    transpose_bf16_kernel<HID, HID><<<dim3(32, 32), dim3(64, 4), 0, stream>>>(Wo, woT);
    transpose_bf16_kernel<HID, DFF><<<dim3(128, 32), dim3(64, 4), 0, stream>>>(W1, w1T);
    transpose_bf16_kernel<DFF, HID><<<dim3(32, 128), dim3(64, 4), 0, stream>>>(W2, w2T);

    // LN1
    ln_kernel<<<MROWS, blk256, 0, stream>>>(x, ln1w, ln1b, h);

    // QKV projections
    gemm_kernel<0, HID, HID><<<dim3(16, 32), blk256, 0, stream>>>(h, wqT, qb, nullptr, nullptr);
    gemm_kernel<0, HID, HID><<<dim3(16, 32), blk256, 0, stream>>>(h, wkT, kb, nullptr, nullptr);
    gemm_kernel<1, HID, HID><<<dim3(16, 32), blk256, 0, stream>>>(h, wvT, vtb, nullptr, nullptr);

    // attention
    attn_kernel<<<dim3(TT / 64, BB * NH), blk256, 0, stream>>>(qb, kb, vtb, attn);

    // output projection + residual
    gemm_kernel<2, HID, HID><<<dim3(16, 32), blk256, 0, stream>>>(attn, woT, x1, x, nullptr);

    // LN2 (h reused as h2)
    ln_kernel<<<MROWS, blk256, 0, stream>>>(x1, ln2w, ln2b, h);

    // MLP
    gemm_kernel<3, DFF, HID><<<dim3(64, 32), blk256, 0, stream>>>(h, w1T, mlp1, nullptr, b1);
    gemm_kernel<4, HID, DFF><<<dim3(16, 32), blk256, 0, stream>>>(mlp1, w2T, outp, x1, b2);
}

// Round 2
// 811.539 us; speedup vs baseline: 1.4020x; 1.4020x over previous
//
#include <hip/hip_runtime.h>

#define HID 2048
#define NH 16
#define DH 128
#define DFF 8192
#define BB 2
#define TT 2048
#define MROWS 4096   // B*T

typedef __bf16 bf16x8 __attribute__((ext_vector_type(8)));
typedef __bf16 bf16x4 __attribute__((ext_vector_type(4)));
typedef float  f32x4  __attribute__((ext_vector_type(4)));

__device__ __forceinline__ f32x4 mfma16(bf16x8 a, bf16x8 b, f32x4 c) {
    return __builtin_amdgcn_mfma_f32_16x16x32_bf16(a, b, c, 0, 0, 0);
}

__device__ __forceinline__ void gload_lds16(const __bf16* gsrc, __bf16* ldst) {
    __builtin_amdgcn_global_load_lds(
        (const __attribute__((address_space(1))) void*)gsrc,
        (__attribute__((address_space(3))) void*)ldst, 16, 0, 0);
}

// ---------------- weight transpose+convert: W[K][N] f32 -> Wt[N][K] bf16 ----
template<int K, int N>
__global__ __launch_bounds__(256) void transpose_bf16_kernel(
    const float* __restrict__ W, __bf16* __restrict__ Wt) {
    __shared__ float tile[64][65];
    int tx = threadIdx.x;          // 0..63
    int ty = threadIdx.y;          // 0..3
    int n0 = blockIdx.x * 64;
    int k0 = blockIdx.y * 64;
    #pragma unroll
    for (int i = 0; i < 16; i++) {
        int kk = ty * 16 + i;
        tile[tx][kk] = W[(size_t)(k0 + kk) * N + n0 + tx];
    }
    __syncthreads();
    #pragma unroll
    for (int i = 0; i < 16; i++) {
        int nn = ty * 16 + i;
        Wt[(size_t)(n0 + nn) * K + k0 + tx] = (__bf16)tile[nn][tx];
    }
}

// ---------------- LayerNorm f32 -> bf16 ------------------------------------
__global__ __launch_bounds__(256) void ln_kernel(
    const float* __restrict__ x, const float* __restrict__ gw,
    const float* __restrict__ gb, __bf16* __restrict__ out) {
    int row = blockIdx.x;
    int t = threadIdx.x;
    const float* xr = x + (size_t)row * HID;
    float4 v0 = *(const float4*)(xr + t * 8);
    float4 v1 = *(const float4*)(xr + t * 8 + 4);
    float xv[8] = {v0.x, v0.y, v0.z, v0.w, v1.x, v1.y, v1.z, v1.w};
    float s = 0.f, q = 0.f;
    #pragma unroll
    for (int j = 0; j < 8; j++) { s += xv[j]; q += xv[j] * xv[j]; }
    #pragma unroll
    for (int off = 1; off < 64; off <<= 1) {
        s += __shfl_xor(s, off);
        q += __shfl_xor(q, off);
    }
    __shared__ float ssum[4], ssq[4];
    if ((t & 63) == 0) { ssum[t >> 6] = s; ssq[t >> 6] = q; }
    __syncthreads();
    s = ssum[0] + ssum[1] + ssum[2] + ssum[3];
    q = ssq[0] + ssq[1] + ssq[2] + ssq[3];
    float mu = s * (1.0f / HID);
    float var = q * (1.0f / HID) - mu * mu;
    float rs = rsqrtf(var + 1e-5f);
    bf16x8 o;
    #pragma unroll
    for (int j = 0; j < 8; j++)
        o[j] = (__bf16)((xv[j] - mu) * rs * gw[t * 8 + j] + gb[t * 8 + j]);
    *(bf16x8*)(out + (size_t)row * HID + t * 8) = o;
}

// ---------------- GEMM: C[M,N] = A[M,K] * Bt[N,K]^T, m97 structure ---------
// EPI: 0=plain bf16, 1=V-transposed bf16 [B,NH,DH,T], 2=f32 +resid,
//      3=bf16 silu(+bias), 4=f32 +bias+resid
template<int EPI, int N, int K>
__global__ __launch_bounds__(256) void gemm_kernel(
    const __bf16* __restrict__ A, const __bf16* __restrict__ Bt,
    void* __restrict__ Cout, const float* __restrict__ resid,
    const float* __restrict__ bias) {
    __shared__ __align__(16) __bf16 As[128 * 32];
    __shared__ __align__(16) __bf16 Bs[128 * 32];
    int tid = threadIdx.x;
    int w = tid >> 6, l = tid & 63;
    int wr = w >> 1, wc = w & 1;
    int qi = l & 15, g = l >> 4;
    int row0 = blockIdx.y * 128, col0 = blockIdx.x * 128;

    f32x4 acc[4][4] = {};

    const __bf16* Abase = A + (size_t)(row0 + w * 32 + (l >> 2)) * K + (l & 3) * 8;
    const __bf16* Bbase = Bt + (size_t)(col0 + w * 32 + (l >> 2)) * K + (l & 3) * 8;

    for (int k0 = 0; k0 < K; k0 += 32) {
        __syncthreads();
        #pragma unroll
        for (int i = 0; i < 2; i++) {
            gload_lds16(Abase + (size_t)i * 16 * K + k0, As + (w * 2 + i) * 512);
            gload_lds16(Bbase + (size_t)i * 16 * K + k0, Bs + (w * 2 + i) * 512);
        }
        __syncthreads();
        bf16x8 af[4], bfr[4];
        #pragma unroll
        for (int m = 0; m < 4; m++)
            af[m] = *(const bf16x8*)(As + (wr * 64 + m * 16 + qi) * 32 + g * 8);
        #pragma unroll
        for (int n = 0; n < 4; n++)
            bfr[n] = *(const bf16x8*)(Bs + (wc * 64 + n * 16 + qi) * 32 + g * 8);
        #pragma unroll
        for (int m = 0; m < 4; m++)
            #pragma unroll
            for (int n = 0; n < 4; n++)
                acc[m][n] = mfma16(af[m], bfr[n], acc[m][n]);
    }

    #pragma unroll
    for (int m = 0; m < 4; m++) {
        #pragma unroll
        for (int n = 0; n < 4; n++) {
            int Rb = row0 + wr * 64 + m * 16 + g * 4;
            int C = col0 + wc * 64 + n * 16 + qi;
            if constexpr (EPI == 1) {
                bf16x4 pk;
                #pragma unroll
                for (int r = 0; r < 4; r++) pk[r] = (__bf16)acc[m][n][r];
                int b = Rb >> 11, t0 = Rb & 2047, hh = C >> 7, d = C & 127;
                *(bf16x4*)((__bf16*)Cout + ((size_t)(b * NH + hh) * DH + d) * TT + t0) = pk;
            } else {
                #pragma unroll
                for (int r = 0; r < 4; r++) {
                    int R = Rb + r;
                    float v = acc[m][n][r];
                    size_t idx = (size_t)R * N + C;
                    if constexpr (EPI == 0) {
                        ((__bf16*)Cout)[idx] = (__bf16)v;
                    } else if constexpr (EPI == 2) {
                        ((float*)Cout)[idx] = resid[idx] + v;
                    } else if constexpr (EPI == 3) {
                        float u = v + bias[C];
                        ((__bf16*)Cout)[idx] = (__bf16)(u / (1.f + __expf(-u)));
                    } else {
                        float u = v + bias[C];
                        ((float*)Cout)[idx] = resid[idx] + u;
                    }
                }
            }
        }
    }
}

// ---------------- flash attention, KVBLK=64 LDS-staged + XOR swizzle --------
// q,k: bf16 [B*T, HID]; vt: bf16 [B,NH,DH,T]; out: bf16 [B*T, HID]
__global__ __launch_bounds__(256) void attn_kernel(
    const __bf16* __restrict__ qh, const __bf16* __restrict__ kh,
    const __bf16* __restrict__ vt, __bf16* __restrict__ out) {
    __shared__ __align__(16) __bf16 Ks[64 * 128];    // [kv][d], swizzled byte^=(kv&7)<<4
    __shared__ __align__(16) __bf16 Vts[128 * 64];   // [d][kv], swizzled byte^=(d&7)<<4
    __shared__ __align__(16) __bf16 plds[4][1024];   // per-wave P[16 q][64 kv], swizzled
    int tid = threadIdx.x;
    int w = tid >> 6, l = tid & 63;
    int qi = l & 15, g = l >> 4;
    int bh = blockIdx.y;
    int b = bh >> 4, hd = bh & 15;
    int qtile = gridDim.x - 1 - blockIdx.x;          // longest blocks first
    int qbase = qtile * 64 + w * 16;
    int qg = qbase + qi;

    const __bf16* qrow = qh + ((size_t)b * TT + qg) * HID + hd * DH;
    const __bf16* kbase = kh + (size_t)b * TT * HID + hd * DH;
    const __bf16* vtb = vt + (size_t)bh * DH * TT;

    bf16x8 bq[4];
    #pragma unroll
    for (int kc = 0; kc < 4; kc++)
        bq[kc] = *(const bf16x8*)(qrow + kc * 32 + g * 8);

    f32x4 O[8] = {};
    float m_run = -3.0e38f, l_run = 0.f;
    const float scale = 0.08838834764831845f;   // 1/sqrt(128)
    int nt = qtile + 1;

    for (int it = 0; it < nt; it++) {
        int kv0 = it * 64;
        __syncthreads();
        // stage K tile: 16KB, swizzled via pre-swizzled global source (rule #21)
        #pragma unroll
        for (int i = 0; i < 4; i++) {
            int j = (w * 4 + i) * 64 + l;            // 16B slot index 0..1023
            int r = j >> 4, u = j & 15;              // row 0..63, 16B-chunk in row
            int cb = (u * 16) ^ ((r & 7) << 4);      // source byte col
            gload_lds16(kbase + (size_t)(kv0 + r) * HID + (cb >> 1),
                        Ks + (w * 4 + i) * 512);
        }
        // stage V^T tile: 16KB
        #pragma unroll
        for (int i = 0; i < 4; i++) {
            int j = (w * 4 + i) * 64 + l;
            int r = j >> 3, u = j & 7;               // row(d) 0..127, chunk in 128B row
            int cb = (u * 16) ^ ((r & 7) << 4);
            gload_lds16(vtb + (size_t)r * TT + kv0 + (cb >> 1),
                        Vts + (w * 4 + i) * 512);
        }
        __syncthreads();                              // drains vmcnt before ds_read

        // QK^T (swapped): st[t] holds S^T rows kv=t*16+g*4+r, col q=qi
        f32x4 st[4] = {};
        #pragma unroll
        for (int t = 0; t < 4; t++) {
            #pragma unroll
            for (int kc = 0; kc < 4; kc++) {
                int row = t * 16 + qi;
                int cb = (kc * 64 + g * 16) ^ ((qi & 7) << 4);
                bf16x8 ak = *(const bf16x8*)(Ks + row * 128 + (cb >> 1));
                st[t] = mfma16(ak, bq[kc], st[t]);
            }
        }
        float s[16];
        #pragma unroll
        for (int t = 0; t < 4; t++)
            #pragma unroll
            for (int r = 0; r < 4; r++) s[t * 4 + r] = st[t][r] * scale;
        #pragma unroll
        for (int i = 0; i < 16; i++) {
            int kvg = kv0 + (i >> 2) * 16 + g * 4 + (i & 3);
            if (kvg > qg) s[i] = -3.0e38f;
        }
        float mt = s[0];
        #pragma unroll
        for (int i = 1; i < 16; i++) mt = fmaxf(mt, s[i]);
        mt = fmaxf(mt, __shfl_xor(mt, 16));
        mt = fmaxf(mt, __shfl_xor(mt, 32));
        float m_new = fmaxf(m_run, mt);
        float alpha = __expf(m_run - m_new);
        float p[16], ps = 0.f;
        #pragma unroll
        for (int i = 0; i < 16; i++) { p[i] = __expf(s[i] - m_new); ps += p[i]; }
        ps += __shfl_xor(ps, 16);
        ps += __shfl_xor(ps, 32);
        l_run = l_run * alpha + ps;
        m_run = m_new;

        // P -> plds (swizzled: row qi stride 128B, byte^=(qi&7)<<4)
        #pragma unroll
        for (int t = 0; t < 4; t++) {
            bf16x4 pk;
            #pragma unroll
            for (int r = 0; r < 4; r++) pk[r] = (__bf16)p[t * 4 + r];
            int cb = (t * 32 + g * 8) ^ ((qi & 7) << 4);
            *(bf16x4*)(&plds[w][qi * 64 + (cb >> 1)]) = pk;
        }

        // rescale O
        float av[4];
        #pragma unroll
        for (int r = 0; r < 4; r++) av[r] = __shfl(alpha, (g << 4) | (g * 4 + r));
        #pragma unroll
        for (int oc = 0; oc < 8; oc++)
            #pragma unroll
            for (int r = 0; r < 4; r++) O[oc][r] *= av[r];

        // PV: O[q=g*4+r][d=oc*16+qi] += P[q][kv] * V^T[d][kv]
        #pragma unroll
        for (int h = 0; h < 2; h++) {
            int cbp = (h * 64 + g * 16) ^ ((qi & 7) << 4);
            bf16x8 ap = *(const bf16x8*)(&plds[w][qi * 64 + (cbp >> 1)]);
            #pragma unroll
            for (int oc = 0; oc < 8; oc++) {
                int row = oc * 16 + qi;
                int cb = (h * 64 + g * 16) ^ ((qi & 7) << 4);
                bf16x8 bv = *(const bf16x8*)(Vts + row * 64 + (cb >> 1));
                O[oc] = mfma16(ap, bv, O[oc]);
            }
        }
    }

    float linv[4];
    #pragma unroll
    for (int r = 0; r < 4; r++) {
        float lq = __shfl(l_run, (g << 4) | (g * 4 + r));
        linv[r] = 1.0f / lq;
    }
    __bf16* op = out + ((size_t)b * TT + qbase) * HID + hd * DH;
    #pragma unroll
    for (int oc = 0; oc < 8; oc++)
        #pragma unroll
        for (int r = 0; r < 4; r++)
            op[(size_t)(g * 4 + r) * HID + oc * 16 + qi] = (__bf16)(O[oc][r] * linv[r]);
}

// ---------------- launch ----------------------------------------------------
extern "C" void kernel_launch(void* const* d_in, const int* in_sizes, int n_in,
                              void* d_out, int out_size, void* d_ws, size_t ws_size,
                              hipStream_t stream) {
    const float* x    = (const float*)d_in[0];
    const float* Wq   = (const float*)d_in[2];
    const float* Wk   = (const float*)d_in[3];
    const float* Wv   = (const float*)d_in[4];
    const float* Wo   = (const float*)d_in[5];
    const float* ln1w = (const float*)d_in[6];
    const float* ln1b = (const float*)d_in[7];
    const float* ln2w = (const float*)d_in[8];
    const float* ln2b = (const float*)d_in[9];
    const float* W1   = (const float*)d_in[10];
    const float* b1   = (const float*)d_in[11];
    const float* W2   = (const float*)d_in[12];
    const float* b2   = (const float*)d_in[13];
    float* outp = (float*)d_out;

    char* ws = (char*)d_ws;
    const size_t SZ_W   = (size_t)HID * HID * 2;
    const size_t SZ_WF  = (size_t)HID * DFF * 2;
    const size_t SZ_ACT = (size_t)MROWS * HID * 2;
    const size_t SZ_X32 = (size_t)MROWS * HID * 4;

    __bf16* wqT  = (__bf16*)(ws);
    __bf16* wkT  = (__bf16*)(ws + SZ_W);
    __bf16* wvT  = (__bf16*)(ws + 2 * SZ_W);
    __bf16* woT  = (__bf16*)(ws + 3 * SZ_W);
    __bf16* w1T  = (__bf16*)(ws + 4 * SZ_W);
    __bf16* w2T  = (__bf16*)(ws + 4 * SZ_W + SZ_WF);
    __bf16* h    = (__bf16*)(ws + 4 * SZ_W + 2 * SZ_WF);            // h2 aliases h
    float*  x1   = (float*) (ws + 4 * SZ_W + 2 * SZ_WF + SZ_ACT);
    char*   base = ws + 4 * SZ_W + 2 * SZ_WF + SZ_ACT + SZ_X32;
    __bf16* qb   = (__bf16*)(base);
    __bf16* kb   = (__bf16*)(base + SZ_ACT);
    __bf16* vtb  = (__bf16*)(base + 2 * SZ_ACT);
    __bf16* attn = (__bf16*)(base + 3 * SZ_ACT);
    __bf16* mlp1 = (__bf16*)(base);                                  // aliases q/k/vt/attn

    dim3 blk256(256);
    transpose_bf16_kernel<HID, HID><<<dim3(32, 32), dim3(64, 4), 0, stream>>>(Wq, wqT);
    transpose_bf16_kernel<HID, HID><<<dim3(32, 32), dim3(64, 4), 0, stream>>>(Wk, wkT);
    transpose_bf16_kernel<HID, HID><<<dim3(32, 32), dim3(64, 4), 0, stream>>>(Wv, wvT);
    transpose_bf16_kernel<HID, HID><<<dim3(32, 32), dim3(64, 4), 0, stream>>>(Wo, woT);
    transpose_bf16_kernel<HID, DFF><<<dim3(128, 32), dim3(64, 4), 0, stream>>>(W1, w1T);
    transpose_bf16_kernel<DFF, HID><<<dim3(32, 128), dim3(64, 4), 0, stream>>>(W2, w2T);

    ln_kernel<<<MROWS, blk256, 0, stream>>>(x, ln1w, ln1b, h);

    gemm_kernel<0, HID, HID><<<dim3(16, 32), blk256, 0, stream>>>(h, wqT, qb, nullptr, nullptr);
    gemm_kernel<0, HID, HID><<<dim3(16, 32), blk256, 0, stream>>>(h, wkT, kb, nullptr, nullptr);
    gemm_kernel<1, HID, HID><<<dim3(16, 32), blk256, 0, stream>>>(h, wvT, vtb, nullptr, nullptr);

    attn_kernel<<<dim3(TT / 64, BB * NH), blk256, 0, stream>>>(qb, kb, vtb, attn);

    gemm_kernel<2, HID, HID><<<dim3(16, 32), blk256, 0, stream>>>(attn, woT, x1, x, nullptr);

    ln_kernel<<<MROWS, blk256, 0, stream>>>(x1, ln2w, ln2b, h);

    gemm_kernel<3, DFF, HID><<<dim3(64, 32), blk256, 0, stream>>>(h, w1T, mlp1, nullptr, b1);
    gemm_kernel<4, HID, DFF><<<dim3(16, 32), blk256, 0, stream>>>(mlp1, w2T, outp, x1, b2);
}

// Round 3
// 765.709 us; speedup vs baseline: 1.4859x; 1.0599x over previous
//
#include <hip/hip_runtime.h>

#define HID 2048
#define NH 16
#define DH 128
#define DFF 8192
#define BB 2
#define TT 2048
#define MROWS 4096   // B*T

typedef __bf16 bf16x8 __attribute__((ext_vector_type(8)));
typedef __bf16 bf16x4 __attribute__((ext_vector_type(4)));
typedef float  f32x4  __attribute__((ext_vector_type(4)));

__device__ __forceinline__ f32x4 mfma16(bf16x8 a, bf16x8 b, f32x4 c) {
    return __builtin_amdgcn_mfma_f32_16x16x32_bf16(a, b, c, 0, 0, 0);
}

__device__ __forceinline__ void gload_lds16(const __bf16* gsrc, __bf16* ldst) {
    __builtin_amdgcn_global_load_lds(
        (const __attribute__((address_space(1))) void*)gsrc,
        (__attribute__((address_space(3))) void*)ldst, 16, 0, 0);
}

// ---------------- weight transpose+convert: W[K][N] f32 -> Wt[N][K] bf16 ----
template<int K, int N>
__global__ __launch_bounds__(256) void transpose_bf16_kernel(
    const float* __restrict__ W, __bf16* __restrict__ Wt) {
    __shared__ float tile[64][65];
    int tx = threadIdx.x;
    int ty = threadIdx.y;
    int n0 = blockIdx.x * 64;
    int k0 = blockIdx.y * 64;
    #pragma unroll
    for (int i = 0; i < 16; i++) {
        int kk = ty * 16 + i;
        tile[tx][kk] = W[(size_t)(k0 + kk) * N + n0 + tx];
    }
    __syncthreads();
    #pragma unroll
    for (int i = 0; i < 16; i++) {
        int nn = ty * 16 + i;
        Wt[(size_t)(n0 + nn) * K + k0 + tx] = (__bf16)tile[nn][tx];
    }
}

// ---------------- LayerNorm f32 -> bf16 ------------------------------------
__global__ __launch_bounds__(256) void ln_kernel(
    const float* __restrict__ x, const float* __restrict__ gw,
    const float* __restrict__ gb, __bf16* __restrict__ out) {
    int row = blockIdx.x;
    int t = threadIdx.x;
    const float* xr = x + (size_t)row * HID;
    float4 v0 = *(const float4*)(xr + t * 8);
    float4 v1 = *(const float4*)(xr + t * 8 + 4);
    float xv[8] = {v0.x, v0.y, v0.z, v0.w, v1.x, v1.y, v1.z, v1.w};
    float s = 0.f, q = 0.f;
    #pragma unroll
    for (int j = 0; j < 8; j++) { s += xv[j]; q += xv[j] * xv[j]; }
    #pragma unroll
    for (int off = 1; off < 64; off <<= 1) {
        s += __shfl_xor(s, off);
        q += __shfl_xor(q, off);
    }
    __shared__ float ssum[4], ssq[4];
    if ((t & 63) == 0) { ssum[t >> 6] = s; ssq[t >> 6] = q; }
    __syncthreads();
    s = ssum[0] + ssum[1] + ssum[2] + ssum[3];
    q = ssq[0] + ssq[1] + ssq[2] + ssq[3];
    float mu = s * (1.0f / HID);
    float var = q * (1.0f / HID) - mu * mu;
    float rs = rsqrtf(var + 1e-5f);
    bf16x8 o;
    #pragma unroll
    for (int j = 0; j < 8; j++)
        o[j] = (__bf16)((xv[j] - mu) * rs * gw[t * 8 + j] + gb[t * 8 + j]);
    *(bf16x8*)(out + (size_t)row * HID + t * 8) = o;
}

// ---------------- 8-wave pipelined GEMM: C[M,N] = A[M,K] * Bt[N,K]^T --------
// BM=256 fixed. 3-deep LDS rotation, counted vmcnt, 1 barrier/K-step,
// XOR-swizzled LDS (both sides), setprio around MFMA, XCD block swizzle.
// EPI: 0=plain bf16, 2=f32 +resid, 3=bf16 silu(+bias), 4=f32 +bias+resid,
//      6=QKV split (C0=q bf16, C1=k bf16, C2=v transposed [B,NH,DH,T])
template<int EPI, int BN, int BK, int N, int K>
__global__ __launch_bounds__(512) void gemm8(
    const __bf16* __restrict__ A, const __bf16* __restrict__ Bt,
    void* __restrict__ C0, void* __restrict__ C1, void* __restrict__ C2,
    const float* __restrict__ resid, const float* __restrict__ bias, int nN) {
    constexpr int BM = 256;
    constexpr int CPR = BK / 8;                 // 16B chunks per LDS row
    constexpr int RND_A = BM * BK * 2 / 8192;   // staging rounds (512thr x 16B)
    constexpr int RND_B = BN * BK * 2 / 8192;
    constexpr int LPT = RND_A + RND_B;          // loads/thread/tile
    constexpr int NT = K / BK;
    constexpr int WC = BN / 4;                  // wave col span
    constexpr int NFRAG = WC / 16;
    constexpr int KK = BK / 32;

    __shared__ __align__(16) __bf16 As[3][BM * BK];
    __shared__ __align__(16) __bf16 Bs[3][BN * BK];

    int tid = threadIdx.x;
    int w = tid >> 6, l = tid & 63;
    int wr = w >> 2, wc = w & 3;
    int qi = l & 15, g = l >> 4;

    int nwg = gridDim.x;
    int bid = blockIdx.x;
    int wg = (bid & 7) * (nwg >> 3) + (bid >> 3);   // XCD swizzle (nwg%8==0)
    int bm = wg / nN, bn = wg % nN;
    int row0 = bm * BM, col0 = bn * BN;

    // per-thread staging source pointers (pre-swizzled chunk, rule #21)
    const __bf16* pA[RND_A];
    #pragma unroll
    for (int i = 0; i < RND_A; i++) {
        int slot = i * 512 + tid;
        int r = slot / CPR, u = slot % CPR;
        pA[i] = A + (size_t)(row0 + r) * K + (u ^ (r & (CPR - 1))) * 8;
    }
    const __bf16* pB[RND_B];
    #pragma unroll
    for (int i = 0; i < RND_B; i++) {
        int slot = i * 512 + tid;
        int r = slot / CPR, u = slot % CPR;
        pB[i] = Bt + (size_t)(col0 + r) * K + (u ^ (r & (CPR - 1))) * 8;
    }
    int wbase = w * 64 * 8;   // wave-uniform LDS dest base (elements)

    f32x4 acc[8][NFRAG] = {};

    // prologue: stage tiles 0,1
    #pragma unroll
    for (int tt = 0; tt < 2; tt++) {
        #pragma unroll
        for (int i = 0; i < RND_A; i++)
            gload_lds16(pA[i] + tt * BK, &As[tt][i * 4096 + wbase]);
        #pragma unroll
        for (int i = 0; i < RND_B; i++)
            gload_lds16(pB[i] + tt * BK, &Bs[tt][i * 4096 + wbase]);
    }

    __bf16 *a0 = As[0], *a1 = As[1], *a2 = As[2];
    __bf16 *b0 = Bs[0], *b1 = Bs[1], *b2 = Bs[2];

    for (int t = 0; t < NT; t++) {
        // tile t landed when <= LPT (tile t+1's loads) outstanding — counted, never 0
        if constexpr (LPT == 6) asm volatile("s_waitcnt vmcnt(6)" ::: "memory");
        else                    asm volatile("s_waitcnt vmcnt(4)" ::: "memory");
        __builtin_amdgcn_s_barrier();
        asm volatile("" ::: "memory");
        if (t + 2 < NT) {   // stage tile t+2 into slot that held tile t-1
            #pragma unroll
            for (int i = 0; i < RND_A; i++)
                gload_lds16(pA[i] + (t + 2) * BK, a2 + i * 4096 + wbase);
            #pragma unroll
            for (int i = 0; i < RND_B; i++)
                gload_lds16(pB[i] + (t + 2) * BK, b2 + i * 4096 + wbase);
        }
        bf16x8 af[8][KK], bfr[NFRAG][KK];
        #pragma unroll
        for (int m = 0; m < 8; m++) {
            int r = wr * 128 + m * 16 + qi;
            #pragma unroll
            for (int kk = 0; kk < KK; kk++) {
                int byt = r * (BK * 2) + ((kk * 64 + g * 16) ^ ((r & (CPR - 1)) << 4));
                af[m][kk] = *(const bf16x8*)((const char*)a0 + byt);
            }
        }
        #pragma unroll
        for (int n = 0; n < NFRAG; n++) {
            int r = wc * WC + n * 16 + qi;
            #pragma unroll
            for (int kk = 0; kk < KK; kk++) {
                int byt = r * (BK * 2) + ((kk * 64 + g * 16) ^ ((r & (CPR - 1)) << 4));
                bfr[n][kk] = *(const bf16x8*)((const char*)b0 + byt);
            }
        }
        __builtin_amdgcn_s_setprio(1);
        #pragma unroll
        for (int kk = 0; kk < KK; kk++)
            #pragma unroll
            for (int m = 0; m < 8; m++)
                #pragma unroll
                for (int n = 0; n < NFRAG; n++)
                    acc[m][n] = mfma16(af[m][kk], bfr[n][kk], acc[m][n]);
        __builtin_amdgcn_s_setprio(0);
        asm volatile("" ::: "memory");
        __bf16* ta = a0; a0 = a1; a1 = a2; a2 = ta;
        __bf16* tb = b0; b0 = b1; b1 = b2; b2 = tb;
    }

    // epilogue: D layout col=lane&15, row=(lane>>4)*4+r
    #pragma unroll
    for (int m = 0; m < 8; m++) {
        #pragma unroll
        for (int n = 0; n < NFRAG; n++) {
            int Rb = row0 + wr * 128 + m * 16 + g * 4;
            int C = col0 + wc * WC + n * 16 + qi;
            if constexpr (EPI == 6) {
                int region = C >> 11;        // uniform per block (BN=128 | 2048)
                int Cl = C & 2047;
                if (region < 2) {
                    __bf16* dst = (__bf16*)(region == 0 ? C0 : C1);
                    #pragma unroll
                    for (int r = 0; r < 4; r++)
                        dst[(size_t)(Rb + r) * 2048 + Cl] = (__bf16)acc[m][n][r];
                } else {
                    bf16x4 pk;
                    #pragma unroll
                    for (int r = 0; r < 4; r++) pk[r] = (__bf16)acc[m][n][r];
                    int b = Rb >> 11, t0 = Rb & 2047, hh = Cl >> 7, d = Cl & 127;
                    *(bf16x4*)((__bf16*)C2 + ((size_t)(b * NH + hh) * DH + d) * TT + t0) = pk;
                }
            } else {
                #pragma unroll
                for (int r = 0; r < 4; r++) {
                    int R = Rb + r;
                    float v = acc[m][n][r];
                    size_t idx = (size_t)R * N + C;
                    if constexpr (EPI == 0) {
                        ((__bf16*)C0)[idx] = (__bf16)v;
                    } else if constexpr (EPI == 2) {
                        ((float*)C0)[idx] = resid[idx] + v;
                    } else if constexpr (EPI == 3) {
                        float u = v + bias[C];
                        ((__bf16*)C0)[idx] = (__bf16)(u / (1.f + __expf(-u)));
                    } else if constexpr (EPI == 4) {
                        float u = v + bias[C];
                        ((float*)C0)[idx] = resid[idx] + u;
                    }
                }
            }
        }
    }
}

// ---------------- flash attention, KVBLK=64 LDS-staged + XOR swizzle --------
__global__ __launch_bounds__(256) void attn_kernel(
    const __bf16* __restrict__ qh, const __bf16* __restrict__ kh,
    const __bf16* __restrict__ vt, __bf16* __restrict__ out) {
    __shared__ __align__(16) __bf16 Ks[64 * 128];
    __shared__ __align__(16) __bf16 Vts[128 * 64];
    __shared__ __align__(16) __bf16 plds[4][1024];
    int tid = threadIdx.x;
    int w = tid >> 6, l = tid & 63;
    int qi = l & 15, g = l >> 4;
    int bh = blockIdx.y;
    int b = bh >> 4, hd = bh & 15;
    int qtile = gridDim.x - 1 - blockIdx.x;
    int qbase = qtile * 64 + w * 16;
    int qg = qbase + qi;

    const __bf16* qrow = qh + ((size_t)b * TT + qg) * HID + hd * DH;
    const __bf16* kbase = kh + (size_t)b * TT * HID + hd * DH;
    const __bf16* vtb = vt + (size_t)bh * DH * TT;

    bf16x8 bq[4];
    #pragma unroll
    for (int kc = 0; kc < 4; kc++)
        bq[kc] = *(const bf16x8*)(qrow + kc * 32 + g * 8);

    f32x4 O[8] = {};
    float m_run = -3.0e38f, l_run = 0.f;
    const float scale = 0.08838834764831845f;
    int nt = qtile + 1;

    for (int it = 0; it < nt; it++) {
        int kv0 = it * 64;
        __syncthreads();
        #pragma unroll
        for (int i = 0; i < 4; i++) {
            int j = (w * 4 + i) * 64 + l;
            int r = j >> 4, u = j & 15;
            int cb = (u * 16) ^ ((r & 7) << 4);
            gload_lds16(kbase + (size_t)(kv0 + r) * HID + (cb >> 1),
                        Ks + (w * 4 + i) * 512);
        }
        #pragma unroll
        for (int i = 0; i < 4; i++) {
            int j = (w * 4 + i) * 64 + l;
            int r = j >> 3, u = j & 7;
            int cb = (u * 16) ^ ((r & 7) << 4);
            gload_lds16(vtb + (size_t)r * TT + kv0 + (cb >> 1),
                        Vts + (w * 4 + i) * 512);
        }
        __syncthreads();

        f32x4 st[4] = {};
        #pragma unroll
        for (int t = 0; t < 4; t++) {
            #pragma unroll
            for (int kc = 0; kc < 4; kc++) {
                int row = t * 16 + qi;
                int cb = (kc * 64 + g * 16) ^ ((qi & 7) << 4);
                bf16x8 ak = *(const bf16x8*)(Ks + row * 128 + (cb >> 1));
                st[t] = mfma16(ak, bq[kc], st[t]);
            }
        }
        float s[16];
        #pragma unroll
        for (int t = 0; t < 4; t++)
            #pragma unroll
            for (int r = 0; r < 4; r++) s[t * 4 + r] = st[t][r] * scale;
        #pragma unroll
        for (int i = 0; i < 16; i++) {
            int kvg = kv0 + (i >> 2) * 16 + g * 4 + (i & 3);
            if (kvg > qg) s[i] = -3.0e38f;
        }
        float mt = s[0];
        #pragma unroll
        for (int i = 1; i < 16; i++) mt = fmaxf(mt, s[i]);
        mt = fmaxf(mt, __shfl_xor(mt, 16));
        mt = fmaxf(mt, __shfl_xor(mt, 32));
        float m_new = fmaxf(m_run, mt);
        float alpha = __expf(m_run - m_new);
        float p[16], ps = 0.f;
        #pragma unroll
        for (int i = 0; i < 16; i++) { p[i] = __expf(s[i] - m_new); ps += p[i]; }
        ps += __shfl_xor(ps, 16);
        ps += __shfl_xor(ps, 32);
        l_run = l_run * alpha + ps;
        m_run = m_new;

        #pragma unroll
        for (int t = 0; t < 4; t++) {
            bf16x4 pk;
            #pragma unroll
            for (int r = 0; r < 4; r++) pk[r] = (__bf16)p[t * 4 + r];
            int cb = (t * 32 + g * 8) ^ ((qi & 7) << 4);
            *(bf16x4*)(&plds[w][qi * 64 + (cb >> 1)]) = pk;
        }

        float av[4];
        #pragma unroll
        for (int r = 0; r < 4; r++) av[r] = __shfl(alpha, (g << 4) | (g * 4 + r));
        #pragma unroll
        for (int oc = 0; oc < 8; oc++)
            #pragma unroll
            for (int r = 0; r < 4; r++) O[oc][r] *= av[r];

        #pragma unroll
        for (int h = 0; h < 2; h++) {
            int cbp = (h * 64 + g * 16) ^ ((qi & 7) << 4);
            bf16x8 ap = *(const bf16x8*)(&plds[w][qi * 64 + (cbp >> 1)]);
            #pragma unroll
            for (int oc = 0; oc < 8; oc++) {
                int row = oc * 16 + qi;
                int cb = (h * 64 + g * 16) ^ ((qi & 7) << 4);
                bf16x8 bv = *(const bf16x8*)(Vts + row * 64 + (cb >> 1));
                O[oc] = mfma16(ap, bv, O[oc]);
            }
        }
    }

    float linv[4];
    #pragma unroll
    for (int r = 0; r < 4; r++) {
        float lq = __shfl(l_run, (g << 4) | (g * 4 + r));
        linv[r] = 1.0f / lq;
    }
    __bf16* op = out + ((size_t)b * TT + qbase) * HID + hd * DH;
    #pragma unroll
    for (int oc = 0; oc < 8; oc++)
        #pragma unroll
        for (int r = 0; r < 4; r++)
            op[(size_t)(g * 4 + r) * HID + oc * 16 + qi] = (__bf16)(O[oc][r] * linv[r]);
}

// ---------------- launch ----------------------------------------------------
extern "C" void kernel_launch(void* const* d_in, const int* in_sizes, int n_in,
                              void* d_out, int out_size, void* d_ws, size_t ws_size,
                              hipStream_t stream) {
    const float* x    = (const float*)d_in[0];
    const float* Wq   = (const float*)d_in[2];
    const float* Wk   = (const float*)d_in[3];
    const float* Wv   = (const float*)d_in[4];
    const float* Wo   = (const float*)d_in[5];
    const float* ln1w = (const float*)d_in[6];
    const float* ln1b = (const float*)d_in[7];
    const float* ln2w = (const float*)d_in[8];
    const float* ln2b = (const float*)d_in[9];
    const float* W1   = (const float*)d_in[10];
    const float* b1   = (const float*)d_in[11];
    const float* W2   = (const float*)d_in[12];
    const float* b2   = (const float*)d_in[13];
    float* outp = (float*)d_out;

    char* ws = (char*)d_ws;
    const size_t SZ_W   = (size_t)HID * HID * 2;
    const size_t SZ_WF  = (size_t)HID * DFF * 2;
    const size_t SZ_ACT = (size_t)MROWS * HID * 2;
    const size_t SZ_X32 = (size_t)MROWS * HID * 4;

    __bf16* wqT  = (__bf16*)(ws);                   // wq|wk|wv contiguous = fused [6144][2048]
    __bf16* wkT  = (__bf16*)(ws + SZ_W);
    __bf16* wvT  = (__bf16*)(ws + 2 * SZ_W);
    __bf16* woT  = (__bf16*)(ws + 3 * SZ_W);
    __bf16* w1T  = (__bf16*)(ws + 4 * SZ_W);
    __bf16* w2T  = (__bf16*)(ws + 4 * SZ_W + SZ_WF);
    __bf16* h    = (__bf16*)(ws + 4 * SZ_W + 2 * SZ_WF);
    float*  x1   = (float*) (ws + 4 * SZ_W + 2 * SZ_WF + SZ_ACT);
    char*   base = ws + 4 * SZ_W + 2 * SZ_WF + SZ_ACT + SZ_X32;
    __bf16* qb   = (__bf16*)(base);
    __bf16* kb   = (__bf16*)(base + SZ_ACT);
    __bf16* vtb  = (__bf16*)(base + 2 * SZ_ACT);
    __bf16* attn = (__bf16*)(base + 3 * SZ_ACT);
    __bf16* mlp1 = (__bf16*)(base);                  // aliases q/k/vt/attn

    dim3 blk256(256), blk512(512);
    transpose_bf16_kernel<HID, HID><<<dim3(32, 32), dim3(64, 4), 0, stream>>>(Wq, wqT);
    transpose_bf16_kernel<HID, HID><<<dim3(32, 32), dim3(64, 4), 0, stream>>>(Wk, wkT);
    transpose_bf16_kernel<HID, HID><<<dim3(32, 32), dim3(64, 4), 0, stream>>>(Wv, wvT);
    transpose_bf16_kernel<HID, HID><<<dim3(32, 32), dim3(64, 4), 0, stream>>>(Wo, woT);
    transpose_bf16_kernel<HID, DFF><<<dim3(128, 32), dim3(64, 4), 0, stream>>>(W1, w1T);
    transpose_bf16_kernel<DFF, HID><<<dim3(32, 128), dim3(64, 4), 0, stream>>>(W2, w2T);

    ln_kernel<<<MROWS, blk256, 0, stream>>>(x, ln1w, ln1b, h);

    // fused QKV: N=6144, BN=128 -> 16x48 = 768 blocks (3 full CU-waves)
    gemm8<6, 128, 64, 6144, HID><<<768, blk512, 0, stream>>>(
        h, wqT, qb, kb, vtb, nullptr, nullptr, 48);

    attn_kernel<<<dim3(TT / 64, BB * NH), blk256, 0, stream>>>(qb, kb, vtb, attn);

    // O projection + residual: 16x16 = 256 blocks
    gemm8<2, 128, 64, HID, HID><<<256, blk512, 0, stream>>>(
        attn, woT, x1, nullptr, nullptr, x, nullptr, 16);

    ln_kernel<<<MROWS, blk256, 0, stream>>>(x1, ln2w, ln2b, h);

    // MLP1: N=8192, BN=256 -> 16x32 = 512 blocks
    gemm8<3, 256, 32, DFF, HID><<<512, blk512, 0, stream>>>(
        h, w1T, mlp1, nullptr, nullptr, nullptr, b1, 32);
    // MLP2: K=8192, BN=128 -> 16x16 = 256 blocks
    gemm8<4, 128, 64, HID, DFF><<<256, blk512, 0, stream>>>(
        mlp1, w2T, outp, nullptr, nullptr, x1, b2, 16);
}